// Round 7
// baseline (365.756 us; speedup 1.0000x reference)
//
#include <hip/hip_runtime.h>

typedef _Float16 h2 __attribute__((ext_vector_type(2)));

struct __align__(4) Px { h2 rg; h2 bq; float n; };  // 12 B: (r,g | b,q | n)

#define HH 480
#define WW 854
#define HWSZ (HH * WW)
#define PAD 192                 // = 3 * max dilation (64)
#define PSTR 1240               // padded row stride
#define PH (HH + 2 * PAD)       // 864
#define PCELLS (PH * PSTR)      // 1,071,360 cells

// workspace layout (bytes)
#define OFF_QA 12856320u                 // after P (PCELLS*12)
#define OFF_QS 14999040u                 // qA + PCELLS*2
#define OFF_E  17141760u                 // qS + PCELLS*2
#define QSD    (OFF_QS - OFF_QA)         // 2,142,720
#define E_BYTES 146751360u               // 179 * HWSZ * 2
#define WS_NEED ((size_t)OFF_E + (size_t)E_BYTES)
#define EPLANE 819840u                   // HWSZ*2 bytes per tap plane

#if __has_builtin(__builtin_amdgcn_exp2f)
#define EXP2(x) __builtin_amdgcn_exp2f(x)
#else
#define EXP2(x) exp2f(x)
#endif

__device__ __forceinline__ float fdot2f(h2 a, h2 b, float c)
{
#if __has_builtin(__builtin_amdgcn_fdot2)
    return __builtin_amdgcn_fdot2(a, b, c, false);
#else
    return fmaf((float)a.x, (float)b.x, fmaf((float)a.y, (float)b.y, c));
#endif
}

__device__ __forceinline__ h2 bch2(unsigned u)
{
    union { unsigned u; h2 h; } v; v.u = u; return v.h;
}
__device__ __forceinline__ unsigned h2u(h2 h)
{
    union { h2 h; unsigned u; } v; v.h = h; return v.u;
}
__device__ __forceinline__ float hiq(unsigned u)
{
    union { unsigned u; h2 h; } v; v.u = u; return (float)v.h.y;
}
__device__ __forceinline__ unsigned short hbits(_Float16 h)
{
    union { _Float16 h; unsigned short u; } v; v.h = h; return v.u;
}

// ---------------------------------------------------------------------------
// Sentinel fill for P: pad cells n = 1e30 -> exp2(-huge) = 0 contribution.
// ---------------------------------------------------------------------------
__global__ __launch_bounds__(256) void fill_sent(unsigned* __restrict__ W)
{
    int i = blockIdx.x * 256 + threadIdx.x;
    if (i < PCELLS * 3) W[i] = (i % 3 == 2) ? 0x7149F2CAu : 0u;  // 1e30f
}

// ---------------------------------------------------------------------------
// Build P once (rgb f16-rounded, pre-scaled by kernel-0 scales; n from the
// ROUNDED rgb). q slot unused by the fast path.
// ---------------------------------------------------------------------------
__global__ __launch_bounds__(256) void build_P(
    const float* __restrict__ xrgb, const float* __restrict__ fs,
    Px* __restrict__ P)
{
    int i = blockIdx.x * 256 + threadIdx.x;
    if (i >= HWSZ) return;
    _Float16 rh = (_Float16)(xrgb[i] * (1.0f / fs[2]));
    _Float16 gh = (_Float16)(xrgb[HWSZ + i] * (1.0f / fs[3]));
    _Float16 bh = (_Float16)(xrgb[2 * HWSZ + i] * (1.0f / fs[4]));
    float rf = (float)rh, gf = (float)gh, bf = (float)bh;
    Px v;
    v.rg = h2{rh, gh};
    v.bq = h2{bh, (_Float16)0};
    v.n = fmaf(rf, rf, fmaf(gf, gf, bf * bf));
    int y = i / WW, x = i - y * WW;
    P[(y + PAD) * PSTR + x + PAD] = v;
}

// ---------------------------------------------------------------------------
// Pass: precompute all 179 kernel maps E[t][p] = K_t(p) as f16 (step-invariant;
// w NOT folded in). PX=2 per lane; biased exp2 + per-center factor keeps all
// intermediates in f32 range, product = true K in [0,1].
// ---------------------------------------------------------------------------
__global__ __launch_bounds__(256) void pass_E(
    const Px* __restrict__ P, const float* __restrict__ fs,
    ushort* __restrict__ E)
{
    __shared__ __align__(16) float tp0[56], tp1[56], tp2[108];
    __shared__ float scal[9];

    const float NH = -0.72134752044448169f;  // -0.5 * log2(e)
    int tid = threadIdx.y * 64 + threadIdx.x;

    float i2 = 255.0f / fs[2], i3 = 255.0f / fs[3], i4 = 255.0f / fs[4];
    float nmax = i2 * i2 + i3 * i3 + i4 * i4;

    if (tid < 49) {                       // kernel 0: 7x7 dil 64
        float C = -0.5f * NH * nmax;
        int dy = tid / 7 - 3, dx = tid % 7 - 3;
        float py = dy * 64.0f / fs[0], px = dx * 64.0f / fs[1];
        tp0[(tid / 7) * 8 + tid % 7] = NH * (py * py + px * px) - C;
    } else if (tid >= 64 && tid < 113) {  // kernel 1: 7x7 dil 16
        int t = tid - 64;
        float r1 = fs[2] / fs[7];
        float C = -0.5f * NH * r1 * r1 * nmax;
        int dy = t / 7 - 3, dx = t % 7 - 3;
        float py = dy * 16.0f / fs[5], px = dx * 16.0f / fs[6];
        tp1[(t / 7) * 8 + t % 7] =
            NH * r1 * r1 * 0.0f + NH * (py * py + px * px) - C;
    } else if (tid >= 128 && tid < 209) { // kernel 2: 9x9 dil 1
        int t = tid - 128;
        float r2 = fs[2] / fs[12];
        float C = -0.5f * NH * r2 * r2 * nmax;
        int dy = t / 9 - 4, dx = t % 9 - 4;
        float py = dy / fs[10], px = dx / fs[11];
        tp2[(t / 9) * 12 + t % 9] = NH * (py * py + px * px) - C;
    } else if (tid == 224) {
        float r1 = fs[2] / fs[7], r2 = fs[2] / fs[12];
        float nk0 = NH, nk1 = NH * r1 * r1, nk2 = NH * r2 * r2;
        scal[0] = nk0; scal[1] = nk1; scal[2] = nk2;
        scal[3] = -2.0f * nk0; scal[4] = -2.0f * nk1; scal[5] = -2.0f * nk2;
        scal[6] = -0.5f * nk0 * nmax;
        scal[7] = -0.5f * nk1 * nmax;
        scal[8] = -0.5f * nk2 * nmax;
    }
    __syncthreads();

    int x0 = (blockIdx.x * 64 + threadIdx.x) * 2;
    int y = blockIdx.y * 4 + threadIdx.y;
    if (x0 >= WW) return;
    int ccell = (y + PAD) * PSTR + x0 + PAD;
    const Px* Pc = P + ccell;
    Px cp0 = Pc[0], cp1 = Pc[1];
    h2 rg0 = cp0.rg, rg1 = cp1.rg;
    h2 mb0 = bch2(h2u(cp0.bq) & 0xFFFFu);
    h2 mb1 = bch2(h2u(cp1.bq) & 0xFFFFu);

    float f00 = EXP2(fmaf(scal[0], cp0.n, scal[6]));
    float f01 = EXP2(fmaf(scal[0], cp1.n, scal[6]));
    float f10 = EXP2(fmaf(scal[1], cp0.n, scal[7]));
    float f11 = EXP2(fmaf(scal[1], cp1.n, scal[7]));
    float f20 = EXP2(fmaf(scal[2], cp0.n, scal[8]));
    float f21 = EXP2(fmaf(scal[2], cp1.n, scal[8]));

    size_t prow = (size_t)((unsigned)(y * WW + x0) >> 1);  // h2 index of pair
    h2* Eh = (h2*)E;
    const size_t PL = HWSZ / 2;   // h2 elements per tap plane

    {   // kernel 0: 7x7 dil 64, taps 0..48
        float nk = scal[0], m2 = scal[3];
#pragma unroll 1
        for (int i = 0; i < 7; ++i) {
            const Px* rp = Pc + (i - 3) * 64 * PSTR;
            h2* ed = Eh + (size_t)(i * 7) * PL + prow;
#pragma unroll
            for (int j = 0; j < 7; ++j) {
                Px q0 = rp[(j - 3) * 64], q1 = rp[(j - 3) * 64 + 1];
                float tpv = tp0[i * 8 + j];
                float e0 = EXP2(fmaf(fdot2f(mb0, q0.bq, fdot2f(rg0, q0.rg, 0.f)),
                                     m2, fmaf(q0.n, nk, tpv))) * f00;
                float e1 = EXP2(fmaf(fdot2f(mb1, q1.bq, fdot2f(rg1, q1.rg, 0.f)),
                                     m2, fmaf(q1.n, nk, tpv))) * f01;
                h2 pr; pr.x = (_Float16)e0; pr.y = (_Float16)e1;
                ed[(size_t)j * PL] = pr;
            }
        }
    }
    {   // kernel 1: 7x7 dil 16, taps 49..97
        float nk = scal[1], m2 = scal[4];
#pragma unroll 1
        for (int i = 0; i < 7; ++i) {
            const Px* rp = Pc + (i - 3) * 16 * PSTR;
            h2* ed = Eh + (size_t)(49 + i * 7) * PL + prow;
#pragma unroll
            for (int j = 0; j < 7; ++j) {
                Px q0 = rp[(j - 3) * 16], q1 = rp[(j - 3) * 16 + 1];
                float tpv = tp1[i * 8 + j];
                float e0 = EXP2(fmaf(fdot2f(mb0, q0.bq, fdot2f(rg0, q0.rg, 0.f)),
                                     m2, fmaf(q0.n, nk, tpv))) * f10;
                float e1 = EXP2(fmaf(fdot2f(mb1, q1.bq, fdot2f(rg1, q1.rg, 0.f)),
                                     m2, fmaf(q1.n, nk, tpv))) * f11;
                h2 pr; pr.x = (_Float16)e0; pr.y = (_Float16)e1;
                ed[(size_t)j * PL] = pr;
            }
        }
    }
    {   // kernel 2: 9x9 dil 1, taps 98..178
        float nk = scal[2], m2 = scal[5];
#pragma unroll 1
        for (int i = 0; i < 9; ++i) {
            const Px* rp = Pc + (i - 4) * PSTR;
            h2* ed = Eh + (size_t)(98 + i * 9) * PL + prow;
#pragma unroll
            for (int j = 0; j < 9; ++j) {
                Px q0 = rp[(j - 4)], q1 = rp[(j - 4) + 1];
                float tpv = tp2[i * 12 + j];
                float e0 = EXP2(fmaf(fdot2f(mb0, q0.bq, fdot2f(rg0, q0.rg, 0.f)),
                                     m2, fmaf(q0.n, nk, tpv))) * f20;
                float e1 = EXP2(fmaf(fdot2f(mb1, q1.bq, fdot2f(rg1, q1.rg, 0.f)),
                                     m2, fmaf(q1.n, nk, tpv))) * f21;
                h2 pr; pr.x = (_Float16)e0; pr.y = (_Float16)e1;
                ed[(size_t)j * PL] = pr;
            }
        }
    }
}

// ---------------------------------------------------------------------------
// Per-step pack: q0 = softmax(logQ)[0] into two f16 planes:
//  qA[c] = q[c]  (dword pair reads at even cells)
//  qS[c] = q[c+1] (serves odd-offset pair reads, alignment-safe)
// ---------------------------------------------------------------------------
__global__ __launch_bounds__(256) void pack_qf(
    const float* __restrict__ src, float scale,
    char* __restrict__ qAb, char* __restrict__ qSb)
{
    int i2 = blockIdx.x * 256 + threadIdx.x;
    if (i2 >= HWSZ / 2) return;
    int p = 2 * i2;
    float l00 = src[p], l10 = src[HWSZ + p];
    float l01 = src[p + 1], l11 = src[HWSZ + p + 1];
    _Float16 q0 = (_Float16)(1.0f / (1.0f + __expf(scale * (l10 - l00))));
    _Float16 q1 = (_Float16)(1.0f / (1.0f + __expf(scale * (l11 - l01))));
    int y = p / WW, x = p - y * WW;
    int c = (y + PAD) * PSTR + x + PAD;   // even
    h2 pr; pr.x = q0; pr.y = q1;
    *(h2*)(qAb + 2 * (size_t)c) = pr;
    ushort* qS = (ushort*)qSb;
    qS[c - 1] = hbits(q0);
    qS[c]     = hbits(q1);
}

// ---------------------------------------------------------------------------
// Fast step: per tap only S = w*E (pk_mul), A += S*q (pk_fma), B += S (pk_add)
// — no exp, no dots. PX=2 per lane; all f16 packed; f32 epilogue.
// ---------------------------------------------------------------------------
__global__ __launch_bounds__(256) void crf_step_fast(
    const ushort* __restrict__ E, const char* __restrict__ qA,
    const float* __restrict__ unary,
    const float* __restrict__ uwArr, const float* __restrict__ pwArr,
    const float* __restrict__ w0, const float* __restrict__ w1,
    const float* __restrict__ w2,
    const float* __restrict__ c0, const float* __restrict__ c1,
    int step, float* __restrict__ out)
{
    __shared__ uint2 tab[179];   // {w duplicated as 2xf16, byte-delta}
    __shared__ float scal[12];

    int tid = threadIdx.y * 64 + threadIdx.x;
    for (int t = tid; t < 179; t += 256) {
        int tl, D, KK; const float* wsrc;
        if (t < 49)      { tl = t;      D = 64; KK = 7; wsrc = w0 + step * 49; }
        else if (t < 98) { tl = t - 49; D = 16; KK = 7; wsrc = w1 + step * 49; }
        else             { tl = t - 98; D = 1;  KK = 9; wsrc = w2 + step * 81; }
        int i = tl / KK, j = tl % KK;
        int dy = (i - KK / 2) * D, dx = (j - KK / 2) * D;
        int dc = dy * PSTR + dx;
        int delta = 2 * dc + ((dx & 1) ? (int)(QSD - 2u) : 0);
        union { _Float16 h[2]; unsigned u; } du;
        du.h[0] = du.h[1] = (_Float16)wsrc[tl];
        tab[t] = make_uint2(du.u, (unsigned)delta);
    }
    if (tid == 192) {
        scal[0] = c0[step * 4 + 0];  scal[1] = c0[step * 4 + 1];
        scal[2] = c0[step * 4 + 2];  scal[3] = c0[step * 4 + 3];
        scal[4] = c1[step * 4 + 0];  scal[5] = c1[step * 4 + 1];
        scal[6] = c1[step * 4 + 2];  scal[7] = c1[step * 4 + 3];
        scal[8] = pwArr[step * 3 + 0];
        scal[9] = pwArr[step * 3 + 1];
        scal[10] = pwArr[step * 3 + 2];
        scal[11] = uwArr[step] * 5.0f;
    }
    __syncthreads();

    int x0 = (blockIdx.x * 64 + threadIdx.x) * 2;
    int y = blockIdx.y * 4 + threadIdx.y;
    if (x0 >= WW) return;
    int ccell = (y + PAD) * PSTR + x0 + PAD;
    int p = y * WW + x0;
    unsigned qb = 2u * (unsigned)ccell;
    unsigned ev = 2u * (unsigned)p;
    const char* Eb = (const char*)E;

    h2 a0 = {(_Float16)0, (_Float16)0}, b0 = a0;
    h2 a1 = a0, b1 = a0, a2 = a0, b2 = a0;

#pragma unroll
    for (int t = 0; t < 49; ++t) {
        uint2 tv = tab[t];
        h2 qv = *(const h2*)(qA + (size_t)(qb + tv.y));
        h2 e  = *(const h2*)(Eb + (size_t)ev); ev += EPLANE;
        h2 s = bch2(tv.x) * e;
        a0 += s * qv; b0 += s;
    }
#pragma unroll
    for (int t = 49; t < 98; ++t) {
        uint2 tv = tab[t];
        h2 qv = *(const h2*)(qA + (size_t)(qb + tv.y));
        h2 e  = *(const h2*)(Eb + (size_t)ev); ev += EPLANE;
        h2 s = bch2(tv.x) * e;
        a1 += s * qv; b1 += s;
    }
#pragma unroll
    for (int t = 98; t < 179; ++t) {
        uint2 tv = tab[t];
        h2 qv = *(const h2*)(qA + (size_t)(qb + tv.y));
        h2 e  = *(const h2*)(Eb + (size_t)ev); ev += EPLANE;
        h2 s = bch2(tv.x) * e;
        a2 += s * qv; b2 += s;
    }

    float pw0 = scal[8], pw1 = scal[9], pw2 = scal[10], uw5 = scal[11];
    float2 un0 = *(const float2*)(unary + p);
    float2 un1 = *(const float2*)(unary + HWSZ + p);

    // px0 (low halves)
    float A0 = (float)a0.x, B0 = (float)b0.x;
    float A1 = (float)a1.x, B1 = (float)b1.x;
    float A2 = (float)a2.x, B2 = (float)b2.x;
    float m01 = B0 - A0, m11 = B1 - A1, m21 = B2 - A2;
    float r00 = scal[0] * A0 + scal[1] * m01;
    float r01 = scal[2] * A0 + scal[3] * m01;
    float r10 = scal[4] * A1 + scal[5] * m11;
    float r11 = scal[6] * A1 + scal[7] * m11;
    float o0x = uw5 * un0.x + pw0 * r00 + pw1 * r10 + pw2 * A2;
    float o1x = uw5 * un1.x + pw0 * r01 + pw1 * r11 + pw2 * m21;

    // px1 (high halves)
    float A0y = (float)a0.y, B0y = (float)b0.y;
    float A1y = (float)a1.y, B1y = (float)b1.y;
    float A2y = (float)a2.y, B2y = (float)b2.y;
    float m01y = B0y - A0y, m11y = B1y - A1y, m21y = B2y - A2y;
    float r00y = scal[0] * A0y + scal[1] * m01y;
    float r01y = scal[2] * A0y + scal[3] * m01y;
    float r10y = scal[4] * A1y + scal[5] * m11y;
    float r11y = scal[6] * A1y + scal[7] * m11y;
    float o0y = uw5 * un0.y + pw0 * r00y + pw1 * r10y + pw2 * A2y;
    float o1y = uw5 * un1.y + pw0 * r01y + pw1 * r11y + pw2 * m21y;

    float2 s0; s0.x = o0x; s0.y = o0y;
    float2 s1; s1.x = o1x; s1.y = o1y;
    *(float2*)(out + p) = s0;
    *(float2*)(out + HWSZ + p) = s1;
}

// ===========================================================================
// Fallback path (ws too small): round-4 kernels, verified at absmax 0.125.
// ===========================================================================
__global__ __launch_bounds__(256) void pack_q_fb(
    const float* __restrict__ src, float scale,
    const float* __restrict__ xrgb, const float* __restrict__ fs,
    Px* __restrict__ P)
{
    int i = blockIdx.x * 256 + threadIdx.x;
    if (i >= HWSZ) return;
    float l0 = src[i], l1 = src[HWSZ + i];
    float q0 = 1.0f / (1.0f + __expf(scale * (l1 - l0)));
    _Float16 rh = (_Float16)(xrgb[i] * (1.0f / fs[2]));
    _Float16 gh = (_Float16)(xrgb[HWSZ + i] * (1.0f / fs[3]));
    _Float16 bh = (_Float16)(xrgb[2 * HWSZ + i] * (1.0f / fs[4]));
    float rf = (float)rh, gf = (float)gh, bf = (float)bh;
    Px v;
    v.rg = h2{rh, gh};
    v.bq = h2{bh, (_Float16)q0};
    v.n = fmaf(rf, rf, fmaf(gf, gf, bf * bf));
    int y = i / WW, x = i - y * WW;
    P[(y + PAD) * PSTR + x + PAD] = v;
}

__device__ __forceinline__ void tap_fb(const Px aq, h2 rgp, h2 maskbp,
                                       float nk, float m2nk, float tpv,
                                       float& A, float& B)
{
    float s1 = fdot2f(rgp, aq.rg, 0.0f);
    float dot = fdot2f(maskbp, aq.bq, s1);
    float t = fmaf(aq.n, nk, tpv);
    float arg = fmaf(dot, m2nk, t);
    float e = EXP2(arg);
    A = fmaf(e, hiq(h2u(aq.bq)), A);
    B += e;
}

template <int K, int DIL>
__device__ __forceinline__ void row_fb(const Px* __restrict__ rp,
                                       const float* __restrict__ tr,
                                       h2 rgp, h2 maskbp,
                                       float nk, float m2nk,
                                       float& A, float& B)
{
    Px buf[K];
#pragma unroll
    for (int j = 0; j < K; ++j) buf[j] = rp[(j - K / 2) * DIL];
#pragma unroll
    for (int j = 0; j < K; ++j)
        tap_fb(buf[j], rgp, maskbp, nk, m2nk, tr[j], A, B);
}

__global__ __launch_bounds__(256) void crf_step_fb(
    const Px* __restrict__ P, const float* __restrict__ unary,
    const float* __restrict__ fs, const float* __restrict__ uwArr,
    const float* __restrict__ pwArr,
    const float* __restrict__ w0, const float* __restrict__ w1,
    const float* __restrict__ w2,
    const float* __restrict__ c0, const float* __restrict__ c1,
    int step, float* __restrict__ out)
{
    __shared__ __align__(16) float tp0[7 * 8];
    __shared__ __align__(16) float tp1[7 * 8];
    __shared__ __align__(16) float tp2[9 * 12];
    __shared__ float scal[21];

    const float NH = -0.72134752044448169f;
    int tid = threadIdx.y * 128 + threadIdx.x;

    float i2 = 255.0f / fs[2], i3 = 255.0f / fs[3], i4 = 255.0f / fs[4];
    float nmax = i2 * i2 + i3 * i3 + i4 * i4;

    if (tid < 49) {
        float C = -0.5f * NH * nmax;
        int dy = tid / 7 - 3, dx = tid % 7 - 3;
        float py = dy * 64.0f / fs[0], px = dx * 64.0f / fs[1];
        tp0[(tid / 7) * 8 + tid % 7] =
            log2f(w0[step * 49 + tid]) + NH * (py * py + px * px) - C;
    } else if (tid >= 64 && tid < 113) {
        int t = tid - 64;
        float r1 = fs[2] / fs[7];
        float C = -0.5f * NH * r1 * r1 * nmax;
        int dy = t / 7 - 3, dx = t % 7 - 3;
        float py = dy * 16.0f / fs[5], px = dx * 16.0f / fs[6];
        tp1[(t / 7) * 8 + t % 7] =
            log2f(w1[step * 49 + t]) + NH * (py * py + px * px) - C;
    } else if (tid >= 128 && tid < 209) {
        int t = tid - 128;
        float r2 = fs[2] / fs[12];
        float C = -0.5f * NH * r2 * r2 * nmax;
        int dy = t / 9 - 4, dx = t % 9 - 4;
        float py = dy / fs[10], px = dx / fs[11];
        tp2[(t / 9) * 12 + t % 9] =
            log2f(w2[step * 81 + t]) + NH * (py * py + px * px) - C;
    } else if (tid == 224) {
        float r1 = fs[2] / fs[7], r2 = fs[2] / fs[12];
        float nk0 = NH, nk1 = NH * r1 * r1, nk2 = NH * r2 * r2;
        scal[0] = nk0; scal[1] = nk1; scal[2] = nk2;
        scal[3] = -2.0f * nk0; scal[4] = -2.0f * nk1; scal[5] = -2.0f * nk2;
        scal[6] = -0.5f * nk0 * nmax;
        scal[7] = -0.5f * nk1 * nmax;
        scal[8] = -0.5f * nk2 * nmax;
        scal[9]  = c0[step * 4 + 0];  scal[10] = c0[step * 4 + 1];
        scal[11] = c0[step * 4 + 2];  scal[12] = c0[step * 4 + 3];
        scal[13] = c1[step * 4 + 0];  scal[14] = c1[step * 4 + 1];
        scal[15] = c1[step * 4 + 2];  scal[16] = c1[step * 4 + 3];
        scal[17] = pwArr[step * 3 + 0];
        scal[18] = pwArr[step * 3 + 1];
        scal[19] = pwArr[step * 3 + 2];
        scal[20] = uwArr[step] * 5.0f;
    }
    __syncthreads();

    int x = blockIdx.x * 128 + threadIdx.x;
    int y = blockIdx.y * 2 + threadIdx.y;
    if (x >= WW) return;
    int p = y * WW + x;

    const Px* Pc = P + (y + PAD) * PSTR + (x + PAD);
    Px cp = *Pc;
    h2 rgp = cp.rg;
    h2 maskbp = bch2(h2u(cp.bq) & 0xFFFFu);
    float np = cp.n;

    float nk0 = scal[0], nk1 = scal[1], nk2 = scal[2];
    float m0 = scal[3], m1 = scal[4], m2 = scal[5];

    float A0 = 0.f, B0 = 0.f, A1 = 0.f, B1 = 0.f, A2 = 0.f, B2 = 0.f;

#pragma unroll
    for (int i = 0; i < 9; ++i) {
        if (i < 7) {
            row_fb<7, 64>(Pc + (i - 3) * 64 * PSTR, tp0 + i * 8,
                          rgp, maskbp, nk0, m0, A0, B0);
            row_fb<7, 16>(Pc + (i - 3) * 16 * PSTR, tp1 + i * 8,
                          rgp, maskbp, nk1, m1, A1, B1);
        }
        row_fb<9, 1>(Pc + (i - 4) * PSTR, tp2 + i * 12,
                     rgp, maskbp, nk2, m2, A2, B2);
    }

    float f0 = EXP2(fmaf(nk0, np, scal[6]));
    float f1 = EXP2(fmaf(nk1, np, scal[7]));
    float f2 = EXP2(fmaf(nk2, np, scal[8]));
    float a0 = A0 * f0, b0 = B0 * f0;
    float a1 = A1 * f1, b1 = B1 * f1;
    float a2 = A2 * f2, b2 = B2 * f2;

    float m00 = a0, m01 = b0 - a0;
    float m10 = a1, m11 = b1 - a1;
    float m20 = a2, m21 = b2 - a2;

    float r00 = scal[9]  * m00 + scal[10] * m01;
    float r01 = scal[11] * m00 + scal[12] * m01;
    float r10 = scal[13] * m10 + scal[14] * m11;
    float r11 = scal[15] * m10 + scal[16] * m11;

    float pw0 = scal[17], pw1 = scal[18], pw2 = scal[19], uw5 = scal[20];
    out[p] = uw5 * unary[p] + pw0 * r00 + pw1 * r10 + pw2 * m20;
    out[HWSZ + p] =
        uw5 * unary[HWSZ + p] + pw0 * r01 + pw1 * r11 + pw2 * m21;
}

// ---------------------------------------------------------------------------
extern "C" void kernel_launch(void* const* d_in, const int* in_sizes, int n_in,
                              void* d_out, int out_size, void* d_ws, size_t ws_size,
                              hipStream_t stream)
{
    const float* unary = (const float*)d_in[0];
    const float* xrgb  = (const float*)d_in[1];
    const float* fs    = (const float*)d_in[2];
    const float* uw    = (const float*)d_in[4];
    const float* pw    = (const float*)d_in[5];
    const float* w0    = (const float*)d_in[6];
    const float* w1    = (const float*)d_in[7];
    const float* w2    = (const float*)d_in[8];
    const float* c0    = (const float*)d_in[9];
    const float* c1    = (const float*)d_in[10];
    float* out = (float*)d_out;

    char* base = (char*)d_ws;
    Px* P = (Px*)base;
    char* qA = base + OFF_QA;
    char* qS = base + OFF_QS;
    ushort* E = (ushort*)(base + OFF_E);

    fill_sent<<<(PCELLS * 3 + 255) / 256, 256, 0, stream>>>((unsigned*)d_ws);

    dim3 gs2((WW / 2 + 63) / 64, HH / 4), bs2(64, 4);
    int pxBlocks = (HWSZ + 255) / 256;
    int prBlocks = (HWSZ / 2 + 255) / 256;

    if (ws_size >= WS_NEED) {
        build_P<<<pxBlocks, 256, 0, stream>>>(xrgb, fs, P);
        pass_E<<<gs2, bs2, 0, stream>>>(P, fs, E);
        for (int s = 0; s < 5; ++s) {
            const float* src = (s == 0) ? unary : out;
            float scale = (s == 0) ? 5.0f : 1.0f;
            pack_qf<<<prBlocks, 256, 0, stream>>>(src, scale, qA, qS);
            crf_step_fast<<<gs2, bs2, 0, stream>>>(E, qA, unary, uw, pw,
                                                   w0, w1, w2, c0, c1, s, out);
        }
    } else {
        dim3 gsf((WW + 127) / 128, HH / 2), bsf(128, 2);
        for (int s = 0; s < 5; ++s) {
            const float* src = (s == 0) ? unary : out;
            float scale = (s == 0) ? 5.0f : 1.0f;
            pack_q_fb<<<pxBlocks, 256, 0, stream>>>(src, scale, xrgb, fs, P);
            crf_step_fb<<<gsf, bsf, 0, stream>>>(P, unary, fs, uw, pw,
                                                 w0, w1, w2, c0, c1, s, out);
        }
    }
}

// Round 8
// 194.985 us; speedup vs baseline: 1.8758x; 1.8758x over previous
//
#include <hip/hip_runtime.h>

typedef _Float16 h2 __attribute__((ext_vector_type(2)));

#define HH 480
#define WW 854
#define HWSZ (HH * WW)
#define PAD 192                 // = 3 * max dilation (64)
#define PSTR 1240               // padded row stride (>= 854 + 2*192 = 1238)
#define PH (HH + 2 * PAD)       // 864
#define PCELLS (PH * PSTR)      // 1,071,360 cells * 8 B per plane

#if __has_builtin(__builtin_amdgcn_exp2f)
#define EXP2(x) __builtin_amdgcn_exp2f(x)
#else
#define EXP2(x) exp2f(x)
#endif

__device__ __forceinline__ float fdot2f(h2 a, h2 b, float c)
{
#if __has_builtin(__builtin_amdgcn_fdot2)
    return __builtin_amdgcn_fdot2(a, b, c, false);
#else
    return fmaf((float)a.x, (float)b.x, fmaf((float)a.y, (float)b.y, c));
#endif
}

__device__ __forceinline__ h2 bch2(unsigned u)
{
    union { unsigned u; h2 h; } v; v.u = u; return v.h;
}
__device__ __forceinline__ unsigned h2u(h2 h)
{
    union { h2 h; unsigned u; } v; v.h = h; return v.u;
}
__device__ __forceinline__ float hiq(unsigned u)  // high f16 half -> float
{
    union { unsigned u; h2 h; } v; v.u = u; return (float)v.h.y;
}
__device__ __forceinline__ unsigned short hbits(_Float16 h)
{
    union { _Float16 h; unsigned short u; } v; v.h = h; return v.u;
}

// ---------------------------------------------------------------------------
// Init both ping-pong planes: interior cells get (r,g | b, q=0) with rgb
// f16-rounded and pre-scaled by 1/fs[2..4]; pad cells get the fp16-max
// sentinel (tap diff -> ssq ~ 1.3e10 -> exp2(-1e7) == 0 contribution).
// ---------------------------------------------------------------------------
__global__ __launch_bounds__(256) void init_P(
    const float* __restrict__ xrgb, const float* __restrict__ fs,
    uint2* __restrict__ PA, uint2* __restrict__ PB)
{
    int i = blockIdx.x * 256 + threadIdx.x;
    if (i >= PCELLS) return;
    int y = i / PSTR, x = i - y * PSTR;
    int iy = y - PAD, ix = x - PAD;
    uint2 v;
    if (iy >= 0 && iy < HH && ix >= 0 && ix < WW) {
        int p = iy * WW + ix;
        _Float16 rh = (_Float16)(xrgb[p] * (1.0f / fs[2]));
        _Float16 gh = (_Float16)(xrgb[HWSZ + p] * (1.0f / fs[3]));
        _Float16 bh = (_Float16)(xrgb[2 * HWSZ + p] * (1.0f / fs[4]));
        v = make_uint2(h2u(h2{rh, gh}), h2u(h2{bh, (_Float16)0}));
    } else {
        v = make_uint2(0x7BFF7BFFu, 0x00007BFFu);  // sentinel, q=0
    }
    PA[i] = v;
    PB[i] = v;
}

// ---------------------------------------------------------------------------
// Step-0 q: q0 = softmax(5*unary)[0] merged into plane A's bq words.
// ---------------------------------------------------------------------------
__global__ __launch_bounds__(256) void pack0(
    const float* __restrict__ unary, unsigned* __restrict__ PAw)
{
    int i = blockIdx.x * 256 + threadIdx.x;
    if (i >= HWSZ) return;
    float l0 = unary[i], l1 = unary[HWSZ + i];
    float q = 1.0f / (1.0f + __expf(5.0f * (l1 - l0)));
    int y = i / WW, x = i - y * WW;
    int c = (y + PAD) * PSTR + x + PAD;
    unsigned old = PAw[2 * c + 1];
    PAw[2 * c + 1] = (old & 0xFFFFu) |
                     ((unsigned)hbits((_Float16)q) << 16);
}

// ---------------------------------------------------------------------------
// One tap on an 8-B cell (9 issue ops, R2-verified arithmetic):
//   drg = rg_q - rg_p; dbq = bq_q - bq_p; mask q-lane; ssq via 2x dot2;
//   e = exp2(ssq*nk + tp'); A += e*q_q; B += e.
// ---------------------------------------------------------------------------
__device__ __forceinline__ void tap8(uint2 aq, h2 rgp, h2 bqp, float nk,
                                     float tpv, float& A, float& B)
{
    h2 drg = bch2(aq.x) - rgp;
    h2 dbq = bch2(aq.y) - bqp;
    h2 dbm = bch2(h2u(dbq) & 0xFFFFu);   // (db, 0)
    float s1 = fdot2f(drg, drg, 0.0f);
    float ssq = fdot2f(dbm, dbm, s1);
    float e = EXP2(fmaf(ssq, nk, tpv));
    A = fmaf(e, hiq(aq.y), A);
    B += e;
}

// One row of K taps at dilation D; loads batched first for ILP.
template <int K, int D>
__device__ __forceinline__ void row8(const uint2* __restrict__ rp,
                                     const float* __restrict__ tr,
                                     h2 rgp, h2 bqp, float nk,
                                     float& A, float& B)
{
    uint2 buf[K];
#pragma unroll
    for (int j = 0; j < K; ++j) buf[j] = rp[(j - K / 2) * D];
#pragma unroll
    for (int j = 0; j < K; ++j)
        tap8(buf[j], rgp, bqp, nk, tr[j], A, B);
}

// ---------------------------------------------------------------------------
// Fused step: 3-kernel message passing + compat + logQ update.
// Reads srcP; non-last steps write only q' (one dword) into dstP;
// the last step writes logQ to out. Block = 128x2.
// ---------------------------------------------------------------------------
template <bool LAST>
__global__ __launch_bounds__(256) void crf_step(
    const uint2* __restrict__ srcP, unsigned* __restrict__ dstPw,
    const float* __restrict__ unary,
    const float* __restrict__ fs, const float* __restrict__ uwArr,
    const float* __restrict__ pwArr,
    const float* __restrict__ w0, const float* __restrict__ w1,
    const float* __restrict__ w2,
    const float* __restrict__ c0, const float* __restrict__ c1,
    int step, float* __restrict__ out)
{
    __shared__ __align__(16) float tp0[7 * 8];
    __shared__ __align__(16) float tp1[7 * 8];
    __shared__ __align__(16) float tp2[9 * 12];
    __shared__ float scal[15];

    const float NH = -0.72134752044448169f;  // -0.5 * log2(e)
    int tid = threadIdx.y * 128 + threadIdx.x;

    if (tid < 49) {                       // kernel 0: 7x7 dil 64
        int dy = tid / 7 - 3, dx = tid % 7 - 3;
        float py = dy * 64.0f / fs[0], px = dx * 64.0f / fs[1];
        tp0[(tid / 7) * 8 + tid % 7] =
            log2f(w0[step * 49 + tid]) + NH * (py * py + px * px);
    } else if (tid >= 64 && tid < 113) {  // kernel 1: 7x7 dil 16
        int t = tid - 64;
        int dy = t / 7 - 3, dx = t % 7 - 3;
        float py = dy * 16.0f / fs[5], px = dx * 16.0f / fs[6];
        tp1[(t / 7) * 8 + t % 7] =
            log2f(w1[step * 49 + t]) + NH * (py * py + px * px);
    } else if (tid >= 128 && tid < 209) { // kernel 2: 9x9 dil 1
        int t = tid - 128;
        int dy = t / 9 - 4, dx = t % 9 - 4;
        float py = dy / fs[10], px = dx / fs[11];
        tp2[(t / 9) * 12 + t % 9] =
            log2f(w2[step * 81 + t]) + NH * (py * py + px * px);
    } else if (tid == 224) {
        float r1 = fs[2] / fs[7], r2 = fs[2] / fs[12];
        scal[0] = NH;                   // nk0 (rgb pre-scaled by kernel-0 sc)
        scal[1] = NH * r1 * r1;         // nk1
        scal[2] = NH * r2 * r2;         // nk2
        scal[3] = c0[step * 4 + 0];  scal[4] = c0[step * 4 + 1];
        scal[5] = c0[step * 4 + 2];  scal[6] = c0[step * 4 + 3];
        scal[7] = c1[step * 4 + 0];  scal[8] = c1[step * 4 + 1];
        scal[9] = c1[step * 4 + 2];  scal[10] = c1[step * 4 + 3];
        scal[11] = pwArr[step * 3 + 0];
        scal[12] = pwArr[step * 3 + 1];
        scal[13] = pwArr[step * 3 + 2];
        scal[14] = uwArr[step] * 5.0f;
    }
    __syncthreads();

    int x = blockIdx.x * 128 + threadIdx.x;
    int y = blockIdx.y * 2 + threadIdx.y;
    if (x >= WW) return;
    int p = y * WW + x;
    int ccell = (y + PAD) * PSTR + x + PAD;

    // unary loads issued early so they overlap the tap loops
    float un0 = unary[p], un1 = unary[HWSZ + p];

    const uint2* Pc = srcP + ccell;
    uint2 cw = *Pc;
    h2 rgp = bch2(cw.x);
    h2 bqp = bch2(cw.y);

    float nk0 = scal[0], nk1 = scal[1], nk2 = scal[2];

    float A0 = 0.f, B0 = 0.f, A1 = 0.f, B1 = 0.f, A2 = 0.f, B2 = 0.f;

    // fully static 9-row interleave of the three kernels
#pragma unroll
    for (int i = 0; i < 9; ++i) {
        if (i < 7) {
            row8<7, 64>(Pc + (i - 3) * 64 * PSTR, tp0 + i * 8,
                        rgp, bqp, nk0, A0, B0);
            row8<7, 16>(Pc + (i - 3) * 16 * PSTR, tp1 + i * 8,
                        rgp, bqp, nk1, A1, B1);
        }
        row8<9, 1>(Pc + (i - 4) * PSTR, tp2 + i * 12,
                   rgp, bqp, nk2, A2, B2);
    }

    float m00 = A0, m01 = B0 - A0;
    float m10 = A1, m11 = B1 - A1;
    float m20 = A2, m21 = B2 - A2;

    float r00 = scal[3] * m00 + scal[4] * m01;
    float r01 = scal[5] * m00 + scal[6] * m01;
    float r10 = scal[7] * m10 + scal[8] * m11;
    float r11 = scal[9] * m10 + scal[10] * m11;

    float pw0 = scal[11], pw1 = scal[12], pw2 = scal[13], uw5 = scal[14];
    float o0 = uw5 * un0 + pw0 * r00 + pw1 * r10 + pw2 * m20;
    float o1 = uw5 * un1 + pw0 * r01 + pw1 * r11 + pw2 * m21;

    if (LAST) {
        out[p] = o0;
        out[HWSZ + p] = o1;
    } else {
        float qn = 1.0f / (1.0f + __expf(o1 - o0));
        unsigned nb = (h2u(bqp) & 0xFFFFu) |
                      ((unsigned)hbits((_Float16)qn) << 16);
        dstPw[2 * ccell + 1] = nb;
    }
}

// ---------------------------------------------------------------------------
extern "C" void kernel_launch(void* const* d_in, const int* in_sizes, int n_in,
                              void* d_out, int out_size, void* d_ws, size_t ws_size,
                              hipStream_t stream)
{
    const float* unary = (const float*)d_in[0];
    const float* xrgb  = (const float*)d_in[1];
    const float* fs    = (const float*)d_in[2];
    // d_in[3] = potts_w (dead in reference forward)
    const float* uw    = (const float*)d_in[4];
    const float* pw    = (const float*)d_in[5];
    const float* w0    = (const float*)d_in[6];
    const float* w1    = (const float*)d_in[7];
    const float* w2    = (const float*)d_in[8];
    const float* c0    = (const float*)d_in[9];
    const float* c1    = (const float*)d_in[10];
    float* out = (float*)d_out;

    uint2* PA = (uint2*)d_ws;                               // 8.57 MB
    uint2* PB = (uint2*)((char*)d_ws + (size_t)PCELLS * 8); // 8.57 MB

    init_P<<<(PCELLS + 255) / 256, 256, 0, stream>>>(xrgb, fs, PA, PB);
    pack0<<<(HWSZ + 255) / 256, 256, 0, stream>>>(unary, (unsigned*)PA);

    dim3 gs((WW + 127) / 128, HH / 2), bs(128, 2);
    for (int s = 0; s < 5; ++s) {
        const uint2* src = (s & 1) ? PB : PA;
        unsigned* dst = (unsigned*)((s & 1) ? PA : PB);
        if (s < 4)
            crf_step<false><<<gs, bs, 0, stream>>>(src, dst, unary, fs, uw, pw,
                                                   w0, w1, w2, c0, c1, s, out);
        else
            crf_step<true><<<gs, bs, 0, stream>>>(src, dst, unary, fs, uw, pw,
                                                  w0, w1, w2, c0, c1, s, out);
    }
}

// Round 9
// 185.011 us; speedup vs baseline: 1.9769x; 1.0539x over previous
//
#include <hip/hip_runtime.h>

typedef _Float16 h2 __attribute__((ext_vector_type(2)));

#define HH 480
#define WW 854
#define HWSZ (HH * WW)
#define PAD 192                 // = 3 * max dilation (64)
#define PSTR 1240               // padded row stride
#define PH (HH + 2 * PAD)       // 864
#define PCELLS (PH * PSTR)      // 1,071,360 cells * 8 B per plane
#define TPSTRIDE 240            // floats per step in tp table

#if __has_builtin(__builtin_amdgcn_exp2f)
#define EXP2(x) __builtin_amdgcn_exp2f(x)
#else
#define EXP2(x) exp2f(x)
#endif

__device__ __forceinline__ float fdot2f(h2 a, h2 b, float c)
{
#if __has_builtin(__builtin_amdgcn_fdot2)
    return __builtin_amdgcn_fdot2(a, b, c, false);
#else
    return fmaf((float)a.x, (float)b.x, fmaf((float)a.y, (float)b.y, c));
#endif
}

__device__ __forceinline__ h2 bch2(unsigned u)
{
    union { unsigned u; h2 h; } v; v.u = u; return v.h;
}
__device__ __forceinline__ unsigned h2u(h2 h)
{
    union { h2 h; unsigned u; } v; v.h = h; return v.u;
}
__device__ __forceinline__ float hiq(unsigned u)
{
    union { unsigned u; h2 h; } v; v.u = u; return (float)v.h.y;
}
__device__ __forceinline__ unsigned short hbits(_Float16 h)
{
    union { _Float16 h; unsigned short u; } v; v.h = h; return v.u;
}

// ---------------------------------------------------------------------------
// Init both ping-pong planes (rgb f16, pre-scaled; pad = fp16-max sentinel).
// ---------------------------------------------------------------------------
__global__ __launch_bounds__(256) void init_P(
    const float* __restrict__ xrgb, const float* __restrict__ fs,
    uint2* __restrict__ PA, uint2* __restrict__ PB)
{
    int i = blockIdx.x * 256 + threadIdx.x;
    if (i >= PCELLS) return;
    int y = i / PSTR, x = i - y * PSTR;
    int iy = y - PAD, ix = x - PAD;
    uint2 v;
    if (iy >= 0 && iy < HH && ix >= 0 && ix < WW) {
        int p = iy * WW + ix;
        _Float16 rh = (_Float16)(xrgb[p] * (1.0f / fs[2]));
        _Float16 gh = (_Float16)(xrgb[HWSZ + p] * (1.0f / fs[3]));
        _Float16 bh = (_Float16)(xrgb[2 * HWSZ + p] * (1.0f / fs[4]));
        v = make_uint2(h2u(h2{rh, gh}), h2u(h2{bh, (_Float16)0}));
    } else {
        v = make_uint2(0x7BFF7BFFu, 0x00007BFFu);  // sentinel, q=0
    }
    PA[i] = v;
    PB[i] = v;
}

// ---------------------------------------------------------------------------
// Step-0 q merged into plane A.
// ---------------------------------------------------------------------------
__global__ __launch_bounds__(256) void pack0(
    const float* __restrict__ unary, unsigned* __restrict__ PAw)
{
    int i = blockIdx.x * 256 + threadIdx.x;
    if (i >= HWSZ) return;
    float l0 = unary[i], l1 = unary[HWSZ + i];
    float q = 1.0f / (1.0f + __expf(5.0f * (l1 - l0)));
    int y = i / WW, x = i - y * WW;
    int c = (y + PAD) * PSTR + x + PAD;
    unsigned old = PAw[2 * c + 1];
    PAw[2 * c + 1] = (old & 0xFFFFu) | ((unsigned)hbits((_Float16)q) << 16);
}

// ---------------------------------------------------------------------------
// Precompute per-step tap tables + scalars to global (read back via s_load).
// Per step (TPSTRIDE floats): [0..55] tp0, [56..111] tp1, [112..219] tp2,
// [220..234] scal = {nk0,nk1,nk2, c0[4], c1[4], pw[3], uw5}.
// ---------------------------------------------------------------------------
__global__ __launch_bounds__(256) void build_tp(
    const float* __restrict__ fs, const float* __restrict__ uwArr,
    const float* __restrict__ pwArr,
    const float* __restrict__ w0, const float* __restrict__ w1,
    const float* __restrict__ w2,
    const float* __restrict__ c0, const float* __restrict__ c1,
    float* __restrict__ tp)
{
    int s = blockIdx.x;
    int t = threadIdx.x;
    float* d = tp + s * TPSTRIDE;
    const float NH = -0.72134752044448169f;  // -0.5 * log2(e)

    if (t < 49) {                       // kernel 0: 7x7 dil 64
        int dy = t / 7 - 3, dx = t % 7 - 3;
        float py = dy * 64.0f / fs[0], px = dx * 64.0f / fs[1];
        d[(t / 7) * 8 + t % 7] =
            log2f(w0[s * 49 + t]) + NH * (py * py + px * px);
    } else if (t >= 64 && t < 113) {    // kernel 1: 7x7 dil 16
        int u = t - 64;
        int dy = u / 7 - 3, dx = u % 7 - 3;
        float py = dy * 16.0f / fs[5], px = dx * 16.0f / fs[6];
        d[56 + (u / 7) * 8 + u % 7] =
            log2f(w1[s * 49 + u]) + NH * (py * py + px * px);
    } else if (t >= 128 && t < 209) {   // kernel 2: 9x9 dil 1
        int u = t - 128;
        int dy = u / 9 - 4, dx = u % 9 - 4;
        float py = dy / fs[10], px = dx / fs[11];
        d[112 + (u / 9) * 12 + u % 9] =
            log2f(w2[s * 81 + u]) + NH * (py * py + px * px);
    } else if (t == 224) {
        float r1 = fs[2] / fs[7], r2 = fs[2] / fs[12];
        d[220] = NH;
        d[221] = NH * r1 * r1;
        d[222] = NH * r2 * r2;
        d[223] = c0[s * 4 + 0];  d[224] = c0[s * 4 + 1];
        d[225] = c0[s * 4 + 2];  d[226] = c0[s * 4 + 3];
        d[227] = c1[s * 4 + 0];  d[228] = c1[s * 4 + 1];
        d[229] = c1[s * 4 + 2];  d[230] = c1[s * 4 + 3];
        d[231] = pwArr[s * 3 + 0];
        d[232] = pwArr[s * 3 + 1];
        d[233] = pwArr[s * 3 + 2];
        d[234] = uwArr[s] * 5.0f;
    }
}

// ---------------------------------------------------------------------------
// One tap on an 8-B cell (R2/R8-verified arithmetic).
// ---------------------------------------------------------------------------
__device__ __forceinline__ void tap8(uint2 aq, h2 rgp, h2 bqp, float nk,
                                     float tpv, float& A, float& B)
{
    h2 drg = bch2(aq.x) - rgp;
    h2 dbq = bch2(aq.y) - bqp;
    h2 dbm = bch2(h2u(dbq) & 0xFFFFu);   // (db, 0)
    float s1 = fdot2f(drg, drg, 0.0f);
    float ssq = fdot2f(dbm, dbm, s1);
    float e = EXP2(fmaf(ssq, nk, tpv));
    A = fmaf(e, hiq(aq.y), A);
    B += e;
}

// k0 chunk helpers: static indices only (full unroll).
template <int T0, int N>
__device__ __forceinline__ void loadK0(uint2 (&buf)[N], const uint2* __restrict__ Pc)
{
#pragma unroll
    for (int t = 0; t < N; ++t) {
        const int tt = T0 + t;
        buf[t] = Pc[(tt / 7 - 3) * 64 * PSTR + (tt % 7 - 3) * 64];
    }
}
template <int T0, int N>
__device__ __forceinline__ void compK0(const uint2 (&buf)[N],
                                       const float* __restrict__ tp0,
                                       h2 rgp, h2 bqp, float nk,
                                       float& A, float& B)
{
#pragma unroll
    for (int t = 0; t < N; ++t) {
        const int tt = T0 + t;
        tap8(buf[t], rgp, bqp, nk, tp0[(tt / 7) * 8 + tt % 7], A, B);
    }
}
// k2 chunk from LDS.
template <int T0, int N>
__device__ __forceinline__ void compK2(const uint2* __restrict__ T2b,
                                       const float* __restrict__ tp2,
                                       h2 rgp, h2 bqp, float nk,
                                       float& A, float& B)
{
#pragma unroll
    for (int t = 0; t < N; ++t) {
        const int tt = T0 + t;
        tap8(T2b[(tt / 9) * 136 + tt % 9], rgp, bqp, nk,
             tp2[(tt / 9) * 12 + tt % 9], A, B);
    }
}

// ---------------------------------------------------------------------------
// Fused step. Block = 128x2. k1/k2 from LDS tiles, k0 4-chunk reg-prefetched,
// tap constants via uniform s_load. Non-last steps write only q' (1 dword)
// to the ping-pong plane; last step writes logQ to out.
// ---------------------------------------------------------------------------
template <bool LAST>
__global__ __launch_bounds__(256, 3) void crf_step(
    const uint2* __restrict__ srcP, unsigned* __restrict__ dstPw,
    const float* __restrict__ unary, const float* __restrict__ tpAll,
    int step, float* __restrict__ out)
{
    __shared__ uint2 T1[14 * 224];   // k1 tile: 25088 B
    __shared__ uint2 T2[10 * 136];   // k2 tile: 10880 B

    int tid = threadIdx.y * 128 + threadIdx.x;
    int x0 = blockIdx.x * 128, y0 = blockIdx.y * 2;

    // ---- stage k1 tile (waves 0-1) and k2 tile (waves 2-3) concurrently ----
#pragma unroll
    for (int r = 0; r < 14; ++r) {
        if (tid < 112) {
            int gy = y0 + 16 * (r >> 1) + (r & 1) - 48;
            const uint4* srow = (const uint4*)
                (srcP + (gy + PAD) * PSTR + (x0 - 48 + PAD));
            ((uint4*)T1)[r * 112 + tid] = srow[tid];
        }
    }
#pragma unroll
    for (int r = 0; r < 10; ++r) {
        int t2 = tid - 128;
        if (t2 >= 0 && t2 < 68) {
            int gy = y0 - 4 + r;
            const uint4* srow = (const uint4*)
                (srcP + (gy + PAD) * PSTR + (x0 - 4 + PAD));
            ((uint4*)T2)[r * 68 + t2] = srow[t2];
        }
    }
    __syncthreads();

    int x = x0 + threadIdx.x;
    int y = y0 + threadIdx.y;
    if (x >= WW) return;
    int p = y * WW + x;
    int ccell = (y + PAD) * PSTR + x + PAD;

    // uniform tables -> s_load
    const float* tp0 = tpAll + step * TPSTRIDE;
    const float* tp1 = tp0 + 56;
    const float* tp2 = tp0 + 112;
    const float* sc  = tp0 + 220;
    float nk0 = sc[0], nk1 = sc[1], nk2 = sc[2];

    float un0 = unary[p], un1 = unary[HWSZ + p];

    const uint2* Pc = srcP + ccell;
    uint2 cw = *Pc;
    h2 rgp = bch2(cw.x);
    h2 bqp = bch2(cw.y);

    const uint2* T1b = T1 + threadIdx.y * 224 + threadIdx.x;
    const uint2* T2b = T2 + threadIdx.y * 136 + threadIdx.x;

    float A0 = 0.f, B0 = 0.f, A1 = 0.f, B1 = 0.f, A2 = 0.f, B2 = 0.f;

    // ---- k0 4-chunk register pipeline interleaved with k2 LDS compute ----
    uint2 bA[13], bB[12], bC[12], bD[12];
    loadK0<0, 13>(bA, Pc);
    compK2<0, 20>(T2b, tp2, rgp, bqp, nk2, A2, B2);
    loadK0<13, 12>(bB, Pc);
    compK0<0, 13>(bA, tp0, rgp, bqp, nk0, A0, B0);
    compK2<20, 20>(T2b, tp2, rgp, bqp, nk2, A2, B2);
    loadK0<25, 12>(bC, Pc);
    compK0<13, 12>(bB, tp0, rgp, bqp, nk0, A0, B0);
    compK2<40, 20>(T2b, tp2, rgp, bqp, nk2, A2, B2);
    loadK0<37, 12>(bD, Pc);
    compK0<25, 12>(bC, tp0, rgp, bqp, nk0, A0, B0);
    compK2<60, 21>(T2b, tp2, rgp, bqp, nk2, A2, B2);
    compK0<37, 12>(bD, tp0, rgp, bqp, nk0, A0, B0);

    // ---- k1: 49 taps from LDS ----
#pragma unroll
    for (int i = 0; i < 7; ++i)
#pragma unroll
        for (int j = 0; j < 7; ++j)
            tap8(T1b[i * 448 + j * 16], rgp, bqp, nk1,
                 tp1[i * 8 + j], A1, B1);

    float m00 = A0, m01 = B0 - A0;
    float m10 = A1, m11 = B1 - A1;
    float m20 = A2, m21 = B2 - A2;

    float r00 = sc[3] * m00 + sc[4] * m01;
    float r01 = sc[5] * m00 + sc[6] * m01;
    float r10 = sc[7] * m10 + sc[8] * m11;
    float r11 = sc[9] * m10 + sc[10] * m11;

    float pw0 = sc[11], pw1 = sc[12], pw2 = sc[13], uw5 = sc[14];
    float o0 = uw5 * un0 + pw0 * r00 + pw1 * r10 + pw2 * m20;
    float o1 = uw5 * un1 + pw0 * r01 + pw1 * r11 + pw2 * m21;

    if (LAST) {
        out[p] = o0;
        out[HWSZ + p] = o1;
    } else {
        float qn = 1.0f / (1.0f + __expf(o1 - o0));
        unsigned nb = (h2u(bqp) & 0xFFFFu) |
                      ((unsigned)hbits((_Float16)qn) << 16);
        dstPw[2 * ccell + 1] = nb;
    }
}

// ---------------------------------------------------------------------------
extern "C" void kernel_launch(void* const* d_in, const int* in_sizes, int n_in,
                              void* d_out, int out_size, void* d_ws, size_t ws_size,
                              hipStream_t stream)
{
    const float* unary = (const float*)d_in[0];
    const float* xrgb  = (const float*)d_in[1];
    const float* fs    = (const float*)d_in[2];
    // d_in[3] = potts_w (dead in reference forward)
    const float* uw    = (const float*)d_in[4];
    const float* pw    = (const float*)d_in[5];
    const float* w0    = (const float*)d_in[6];
    const float* w1    = (const float*)d_in[7];
    const float* w2    = (const float*)d_in[8];
    const float* c0    = (const float*)d_in[9];
    const float* c1    = (const float*)d_in[10];
    float* out = (float*)d_out;

    uint2* PA = (uint2*)d_ws;                               // 8.57 MB
    uint2* PB = (uint2*)((char*)d_ws + (size_t)PCELLS * 8); // 8.57 MB
    float* tpAll = (float*)((char*)d_ws + (size_t)PCELLS * 16);

    init_P<<<(PCELLS + 255) / 256, 256, 0, stream>>>(xrgb, fs, PA, PB);
    pack0<<<(HWSZ + 255) / 256, 256, 0, stream>>>(unary, (unsigned*)PA);
    build_tp<<<5, 256, 0, stream>>>(fs, uw, pw, w0, w1, w2, c0, c1, tpAll);

    dim3 gs((WW + 127) / 128, HH / 2), bs(128, 2);
    for (int s = 0; s < 5; ++s) {
        const uint2* src = (s & 1) ? PB : PA;
        unsigned* dst = (unsigned*)((s & 1) ? PA : PB);
        if (s < 4)
            crf_step<false><<<gs, bs, 0, stream>>>(src, dst, unary, tpAll,
                                                   s, out);
        else
            crf_step<true><<<gs, bs, 0, stream>>>(src, dst, unary, tpAll,
                                                  s, out);
    }
}

// Round 10
// 167.840 us; speedup vs baseline: 2.1792x; 1.1023x over previous
//
#include <hip/hip_runtime.h>

typedef _Float16 h2 __attribute__((ext_vector_type(2)));

#define HH 480
#define WW 854
#define HWSZ (HH * WW)
#define PAD 192                 // = 3 * max dilation (64)
#define PSTR 1240               // padded row stride
#define PH (HH + 2 * PAD)       // 864
#define PCELLS (PH * PSTR)      // 1,071,360 cells * 8 B per plane
#define TPSTRIDE 240            // floats per step in tp table

#if __has_builtin(__builtin_amdgcn_exp2f)
#define EXP2(x) __builtin_amdgcn_exp2f(x)
#else
#define EXP2(x) exp2f(x)
#endif

__device__ __forceinline__ float fdot2f(h2 a, h2 b, float c)
{
#if __has_builtin(__builtin_amdgcn_fdot2)
    return __builtin_amdgcn_fdot2(a, b, c, false);
#else
    return fmaf((float)a.x, (float)b.x, fmaf((float)a.y, (float)b.y, c));
#endif
}

__device__ __forceinline__ h2 bch2(unsigned u)
{
    union { unsigned u; h2 h; } v; v.u = u; return v.h;
}
__device__ __forceinline__ unsigned h2u(h2 h)
{
    union { h2 h; unsigned u; } v; v.h = h; return v.u;
}
__device__ __forceinline__ unsigned short hbits(_Float16 h)
{
    union { _Float16 h; unsigned short u; } v; v.h = h; return v.u;
}

// ---------------------------------------------------------------------------
// Init both ping-pong planes (rgb f16, pre-scaled; pad = fp16-max sentinel).
// ---------------------------------------------------------------------------
__global__ __launch_bounds__(256) void init_P(
    const float* __restrict__ xrgb, const float* __restrict__ fs,
    uint2* __restrict__ PA, uint2* __restrict__ PB)
{
    int i = blockIdx.x * 256 + threadIdx.x;
    if (i >= PCELLS) return;
    int y = i / PSTR, x = i - y * PSTR;
    int iy = y - PAD, ix = x - PAD;
    uint2 v;
    if (iy >= 0 && iy < HH && ix >= 0 && ix < WW) {
        int p = iy * WW + ix;
        _Float16 rh = (_Float16)(xrgb[p] * (1.0f / fs[2]));
        _Float16 gh = (_Float16)(xrgb[HWSZ + p] * (1.0f / fs[3]));
        _Float16 bh = (_Float16)(xrgb[2 * HWSZ + p] * (1.0f / fs[4]));
        v = make_uint2(h2u(h2{rh, gh}), h2u(h2{bh, (_Float16)0}));
    } else {
        v = make_uint2(0x7BFF7BFFu, 0x00007BFFu);  // sentinel, q=0
    }
    PA[i] = v;
    PB[i] = v;
}

// ---------------------------------------------------------------------------
// Step-0 q merged into plane A.
// ---------------------------------------------------------------------------
__global__ __launch_bounds__(256) void pack0(
    const float* __restrict__ unary, unsigned* __restrict__ PAw)
{
    int i = blockIdx.x * 256 + threadIdx.x;
    if (i >= HWSZ) return;
    float l0 = unary[i], l1 = unary[HWSZ + i];
    float q = 1.0f / (1.0f + __expf(5.0f * (l1 - l0)));
    int y = i / WW, x = i - y * WW;
    int c = (y + PAD) * PSTR + x + PAD;
    unsigned old = PAw[2 * c + 1];
    PAw[2 * c + 1] = (old & 0xFFFFu) | ((unsigned)hbits((_Float16)q) << 16);
}

// ---------------------------------------------------------------------------
// Precompute per-step tap tables + scalars to global (read back via s_load).
// Per step (TPSTRIDE floats): [0..55] tp0, [56..111] tp1, [112..219] tp2,
// [220..234] scal = {nk0,nk1,nk2, c0[4], c1[4], pw[3], uw5}.
// ---------------------------------------------------------------------------
__global__ __launch_bounds__(256) void build_tp(
    const float* __restrict__ fs, const float* __restrict__ uwArr,
    const float* __restrict__ pwArr,
    const float* __restrict__ w0, const float* __restrict__ w1,
    const float* __restrict__ w2,
    const float* __restrict__ c0, const float* __restrict__ c1,
    float* __restrict__ tp)
{
    int s = blockIdx.x;
    int t = threadIdx.x;
    float* d = tp + s * TPSTRIDE;
    const float NH = -0.72134752044448169f;  // -0.5 * log2(e)

    if (t < 49) {                       // kernel 0: 7x7 dil 64
        int dy = t / 7 - 3, dx = t % 7 - 3;
        float py = dy * 64.0f / fs[0], px = dx * 64.0f / fs[1];
        d[(t / 7) * 8 + t % 7] =
            log2f(w0[s * 49 + t]) + NH * (py * py + px * px);
    } else if (t >= 64 && t < 113) {    // kernel 1: 7x7 dil 16
        int u = t - 64;
        int dy = u / 7 - 3, dx = u % 7 - 3;
        float py = dy * 16.0f / fs[5], px = dx * 16.0f / fs[6];
        d[56 + (u / 7) * 8 + u % 7] =
            log2f(w1[s * 49 + u]) + NH * (py * py + px * px);
    } else if (t >= 128 && t < 209) {   // kernel 2: 9x9 dil 1
        int u = t - 128;
        int dy = u / 9 - 4, dx = u % 9 - 4;
        float py = dy / fs[10], px = dx / fs[11];
        d[112 + (u / 9) * 12 + u % 9] =
            log2f(w2[s * 81 + u]) + NH * (py * py + px * px);
    } else if (t == 224) {
        float r1 = fs[2] / fs[7], r2 = fs[2] / fs[12];
        d[220] = NH;
        d[221] = NH * r1 * r1;
        d[222] = NH * r2 * r2;
        d[223] = c0[s * 4 + 0];  d[224] = c0[s * 4 + 1];
        d[225] = c0[s * 4 + 2];  d[226] = c0[s * 4 + 3];
        d[227] = c1[s * 4 + 0];  d[228] = c1[s * 4 + 1];
        d[229] = c1[s * 4 + 2];  d[230] = c1[s * 4 + 3];
        d[231] = pwArr[s * 3 + 0];
        d[232] = pwArr[s * 3 + 1];
        d[233] = pwArr[s * 3 + 2];
        d[234] = uwArr[s] * 5.0f;
    }
}

// ---------------------------------------------------------------------------
// One tap on an 8-B cell, 8 issue ops:
//   drg = rg_q - rg_p (pk_sub); dbq = bq_q - bq_p (pk_sub)
//   s1 = dot2(drg,drg); ssq = fma_mix(db,db,s1)     [db = lo half of dbq]
//   e = exp2(fma(ssq,nk,tp')); A = fma_mix(e,q_hi,A); B += e
// (f16 squares are exact in f32 -> bit-identical to the dot2+mask form)
// ---------------------------------------------------------------------------
__device__ __forceinline__ void tap8(uint2 aq, h2 rgp, h2 bqp, float nk,
                                     float tpv, float& A, float& B)
{
    h2 drg = bch2(aq.x) - rgp;
    h2 dbq = bch2(aq.y) - bqp;
    float s1 = fdot2f(drg, drg, 0.0f);
    float db = (float)dbq.x;
    float ssq = fmaf(db, db, s1);
    float e = EXP2(fmaf(ssq, nk, tpv));
    A = fmaf(e, (float)bch2(aq.y).y, A);   // q = hi half -> v_fma_mix
    B += e;
}

// k0 chunk helpers: static indices only (full unroll).
template <int T0, int N>
__device__ __forceinline__ void loadK0(uint2 (&buf)[N], const uint2* __restrict__ Pc)
{
#pragma unroll
    for (int t = 0; t < N; ++t) {
        const int tt = T0 + t;
        buf[t] = Pc[(tt / 7 - 3) * 64 * PSTR + (tt % 7 - 3) * 64];
    }
}
template <int T0, int N>
__device__ __forceinline__ void compK0(const uint2 (&buf)[N],
                                       const float* __restrict__ tp0,
                                       h2 rgp, h2 bqp, float nk,
                                       float& A, float& B)
{
#pragma unroll
    for (int t = 0; t < N; ++t) {
        const int tt = T0 + t;
        tap8(buf[t], rgp, bqp, nk, tp0[(tt / 7) * 8 + tt % 7], A, B);
    }
}
// k1 chunk from LDS.
template <int T0, int N>
__device__ __forceinline__ void compK1(const uint2* __restrict__ T1b,
                                       const float* __restrict__ tp1,
                                       h2 rgp, h2 bqp, float nk,
                                       float& A, float& B)
{
#pragma unroll
    for (int t = 0; t < N; ++t) {
        const int tt = T0 + t;
        tap8(T1b[(tt / 7) * 448 + (tt % 7) * 16], rgp, bqp, nk,
             tp1[(tt / 7) * 8 + tt % 7], A, B);
    }
}
// k2 chunk from LDS.
template <int T0, int N>
__device__ __forceinline__ void compK2(const uint2* __restrict__ T2b,
                                       const float* __restrict__ tp2,
                                       h2 rgp, h2 bqp, float nk,
                                       float& A, float& B)
{
#pragma unroll
    for (int t = 0; t < N; ++t) {
        const int tt = T0 + t;
        tap8(T2b[(tt / 9) * 136 + tt % 9], rgp, bqp, nk,
             tp2[(tt / 9) * 12 + tt % 9], A, B);
    }
}

// ---------------------------------------------------------------------------
// Fused step. Block = 128x2. k1/k2 from LDS tiles, k0 4-chunk reg-prefetched
// (chunk A issued pre-barrier), constants via uniform s_load. Non-last steps
// write only q' (1 dword) to the ping-pong plane; last step writes logQ.
// ---------------------------------------------------------------------------
template <bool LAST>
__global__ __launch_bounds__(256, 4) void crf_step(
    const uint2* __restrict__ srcP, unsigned* __restrict__ dstPw,
    const float* __restrict__ unary, const float* __restrict__ tpAll,
    int step, float* __restrict__ out)
{
    __shared__ uint2 T1[14 * 224];   // k1 tile: 25088 B
    __shared__ uint2 T2[10 * 136];   // k2 tile: 10880 B

    int tid = threadIdx.y * 128 + threadIdx.x;
    int x0 = blockIdx.x * 128, y0 = blockIdx.y * 2;

    // ---- stage k1 tile (waves 0-1) and k2 tile (waves 2-3) concurrently ----
#pragma unroll
    for (int r = 0; r < 14; ++r) {
        if (tid < 112) {
            int gy = y0 + 16 * (r >> 1) + (r & 1) - 48;
            const uint4* srow = (const uint4*)
                (srcP + (gy + PAD) * PSTR + (x0 - 48 + PAD));
            ((uint4*)T1)[r * 112 + tid] = srow[tid];
        }
    }
#pragma unroll
    for (int r = 0; r < 10; ++r) {
        int t2 = tid - 128;
        if (t2 >= 0 && t2 < 68) {
            int gy = y0 - 4 + r;
            const uint4* srow = (const uint4*)
                (srcP + (gy + PAD) * PSTR + (x0 - 4 + PAD));
            ((uint4*)T2)[r * 68 + t2] = srow[t2];
        }
    }

    int x = x0 + threadIdx.x;
    int y = y0 + threadIdx.y;
    int p = y * WW + x;
    int ccell = (y + PAD) * PSTR + x + PAD;

    // uniform tables -> s_load (issue early, independent of staging)
    const float* tp0 = tpAll + step * TPSTRIDE;
    const float* tp1 = tp0 + 56;
    const float* tp2 = tp0 + 112;
    const float* sc  = tp0 + 220;
    float nk0 = sc[0], nk1 = sc[1], nk2 = sc[2];

    const uint2* Pc = srcP + ccell;
    uint2 cw = make_uint2(0u, 0u);
    float un0 = 0.f, un1 = 0.f;
    uint2 bA[13];
    bool act = (x < WW);
    if (act) {
        cw = *Pc;
        un0 = unary[p]; un1 = unary[HWSZ + p];
        loadK0<0, 13>(bA, Pc);       // chunk A in flight across the barrier
    }
    __syncthreads();
    if (!act) return;

    h2 rgp = bch2(cw.x);
    h2 bqp = bch2(cw.y);

    const uint2* T1b = T1 + threadIdx.y * 224 + threadIdx.x;
    const uint2* T2b = T2 + threadIdx.y * 136 + threadIdx.x;

    float A0 = 0.f, B0 = 0.f, A1 = 0.f, B1 = 0.f, A2 = 0.f, B2 = 0.f;

    // ---- k0 register pipeline interleaved with k1/k2 LDS compute ----
    uint2 bB[12], bC[12], bD[12];
    loadK0<13, 12>(bB, Pc);
    compK2<0, 20>(T2b, tp2, rgp, bqp, nk2, A2, B2);
    compK0<0, 13>(bA, tp0, rgp, bqp, nk0, A0, B0);
    loadK0<25, 12>(bC, Pc);
    compK2<20, 20>(T2b, tp2, rgp, bqp, nk2, A2, B2);
    compK0<13, 12>(bB, tp0, rgp, bqp, nk0, A0, B0);
    loadK0<37, 12>(bD, Pc);
    compK1<0, 25>(T1b, tp1, rgp, bqp, nk1, A1, B1);
    compK0<25, 12>(bC, tp0, rgp, bqp, nk0, A0, B0);
    compK2<40, 20>(T2b, tp2, rgp, bqp, nk2, A2, B2);
    compK0<37, 12>(bD, tp0, rgp, bqp, nk0, A0, B0);
    compK1<25, 24>(T1b, tp1, rgp, bqp, nk1, A1, B1);
    compK2<60, 21>(T2b, tp2, rgp, bqp, nk2, A2, B2);

    float m00 = A0, m01 = B0 - A0;
    float m10 = A1, m11 = B1 - A1;
    float m20 = A2, m21 = B2 - A2;

    float r00 = sc[3] * m00 + sc[4] * m01;
    float r01 = sc[5] * m00 + sc[6] * m01;
    float r10 = sc[7] * m10 + sc[8] * m11;
    float r11 = sc[9] * m10 + sc[10] * m11;

    float pw0 = sc[11], pw1 = sc[12], pw2 = sc[13], uw5 = sc[14];
    float o0 = uw5 * un0 + pw0 * r00 + pw1 * r10 + pw2 * m20;
    float o1 = uw5 * un1 + pw0 * r01 + pw1 * r11 + pw2 * m21;

    if (LAST) {
        out[p] = o0;
        out[HWSZ + p] = o1;
    } else {
        float qn = 1.0f / (1.0f + __expf(o1 - o0));
        unsigned nb = (h2u(bqp) & 0xFFFFu) |
                      ((unsigned)hbits((_Float16)qn) << 16);
        dstPw[2 * ccell + 1] = nb;
    }
}

// ---------------------------------------------------------------------------
extern "C" void kernel_launch(void* const* d_in, const int* in_sizes, int n_in,
                              void* d_out, int out_size, void* d_ws, size_t ws_size,
                              hipStream_t stream)
{
    const float* unary = (const float*)d_in[0];
    const float* xrgb  = (const float*)d_in[1];
    const float* fs    = (const float*)d_in[2];
    // d_in[3] = potts_w (dead in reference forward)
    const float* uw    = (const float*)d_in[4];
    const float* pw    = (const float*)d_in[5];
    const float* w0    = (const float*)d_in[6];
    const float* w1    = (const float*)d_in[7];
    const float* w2    = (const float*)d_in[8];
    const float* c0    = (const float*)d_in[9];
    const float* c1    = (const float*)d_in[10];
    float* out = (float*)d_out;

    uint2* PA = (uint2*)d_ws;                               // 8.57 MB
    uint2* PB = (uint2*)((char*)d_ws + (size_t)PCELLS * 8); // 8.57 MB
    float* tpAll = (float*)((char*)d_ws + (size_t)PCELLS * 16);

    init_P<<<(PCELLS + 255) / 256, 256, 0, stream>>>(xrgb, fs, PA, PB);
    pack0<<<(HWSZ + 255) / 256, 256, 0, stream>>>(unary, (unsigned*)PA);
    build_tp<<<5, 256, 0, stream>>>(fs, uw, pw, w0, w1, w2, c0, c1, tpAll);

    dim3 gs((WW + 127) / 128, HH / 2), bs(128, 2);
    for (int s = 0; s < 5; ++s) {
        const uint2* src = (s & 1) ? PB : PA;
        unsigned* dst = (unsigned*)((s & 1) ? PA : PB);
        if (s < 4)
            crf_step<false><<<gs, bs, 0, stream>>>(src, dst, unary, tpAll,
                                                   s, out);
        else
            crf_step<true><<<gs, bs, 0, stream>>>(src, dst, unary, tpAll,
                                                  s, out);
    }
}